// Round 1
// baseline (535.987 us; speedup 1.0000x reference)
//
#include <hip/hip_runtime.h>
#include <hip/hip_bf16.h>

#define MIN_NORM 1e-15f
#define EPS 1e-7f
#define MAX_NORM 1000.0f

#define NN 30000
#define PP 4
#define DD 64
#define EE 480000

// ---------- wave-wide helpers (wave = 64 lanes = one point of D=64) ----------
__device__ inline float wsum(float v) {
#pragma unroll
    for (int off = 32; off >= 1; off >>= 1) v += __shfl_xor(v, off, 64);
    return v;
}

// logmap0 (K=1): x point per-lane (lane0 = time). returns tangent per-lane (lane0=0).
__device__ inline float logmap0_pt(float x, int lane) {
    float sp = (lane == 0) ? 0.f : x;
    float n2 = wsum(sp * sp);
    float n = fmaxf(sqrtf(n2), MIN_NORM);
    float x0 = __shfl(x, 0, 64);
    float th = fmaxf(x0, 1.f + EPS);
    float ac = logf(th + sqrtf(fmaxf(th * th - 1.f, MIN_NORM)));
    return (lane == 0) ? 0.f : (ac * sp / n);
}

// expmap0 (K=1) followed by proj: input tangent per-lane (lane0 ignored). returns point.
__device__ inline float expmap0_proj_pt(float v, int lane) {
    float sp = (lane == 0) ? 0.f : v;
    float n2 = wsum(sp * sp);
    float n = fmaxf(sqrtf(n2), MIN_NORM);
    float s = sinhf(n) / n;
    float sq = s * s * n2;                 // ||space||^2 (exact algebraic match to proj)
    float time = sqrtf(fmaxf(1.f + sq, EPS));
    return (lane == 0) ? time : s * sp;
}

// ---------- kernels ----------
__global__ __launch_bounds__(256) void logmap0_kernel(const float* __restrict__ x,
                                                      float* __restrict__ u) {
    int lane = threadIdx.x & 63;
    int w = threadIdx.x >> 6;
    long pt = (long)blockIdx.x * 4 + w;    // point index in [0, N*P)
    float xv = x[pt * 64 + lane];
    u[pt * 64 + lane] = logmap0_pt(xv, lane);
}

__global__ void transpose_kernel(const float* __restrict__ w, float* __restrict__ wt) {
    int j = blockIdx.x;
    int k = threadIdx.x;
    wt[k * 256 + j] = w[j * 256 + k];
}

#define GEMM_R 8
__global__ __launch_bounds__(256) void gemm_kernel(const float* __restrict__ u,
                                                   const float* __restrict__ wt,
                                                   float* __restrict__ mu, int nrows) {
    __shared__ float ulds[GEMM_R][256];
    int tid = threadIdx.x;
    int row0 = blockIdx.x * GEMM_R;
#pragma unroll
    for (int i = 0; i < GEMM_R; i++) {
        int r = row0 + i;
        ulds[i][tid] = (r < nrows) ? u[(size_t)r * 256 + tid] : 0.f;
    }
    __syncthreads();
    float acc[GEMM_R];
#pragma unroll
    for (int i = 0; i < GEMM_R; i++) acc[i] = 0.f;
    for (int k = 0; k < 256; k++) {
        float wv = wt[k * 256 + tid];
#pragma unroll
        for (int i = 0; i < GEMM_R; i++) acc[i] = fmaf(ulds[i][k], wv, acc[i]);
    }
#pragma unroll
    for (int i = 0; i < GEMM_R; i++) {
        int r = row0 + i;
        if (r < nrows) mu[(size_t)r * 256 + tid] = acc[i];
    }
}

// mu -> xt in place: h=expmap0+proj, mobius_add with hyp_bias, proj, logmap0
__global__ __launch_bounds__(256) void hyp_mid_kernel(float* __restrict__ buf,
                                                      const float* __restrict__ bias) {
    int lane = threadIdx.x & 63;
    int w = threadIdx.x >> 6;
    long pt = (long)blockIdx.x * 4 + w;
    int p = (int)(pt & 3);

    float mu = buf[pt * 64 + lane];
    // h = proj(expmap0(proj_tan0(mu)))
    float h = expmap0_proj_pt(mu, lane);
    float h0 = __shfl(h, 0, 64);
    float hs = (lane == 0) ? 0.f : h;

    // hyp_bias = proj(expmap0(proj_tan0(b)))
    float b = bias[p * 64 + lane];
    float y = expmap0_proj_pt(b, lane);
    // u_log = logmap0(y)
    float usp = logmap0_pt(y, lane);       // lane0 = 0

    // ptransp0(h, u_log): v = [-yn, (1-h0)*yu], alpha = dot(yu, usp)
    float yn = fmaxf(sqrtf(wsum(hs * hs)), MIN_NORM);
    float yu = hs / yn;
    float alpha = wsum((lane == 0) ? 0.f : (yu * usp));
    float wsp = (lane == 0) ? 0.f : (usp - alpha * (1.f - h0) * yu);

    // proj_tan(w, h): t = dot(h_sp, w_sp)/max(h0, MIN)
    float ux = wsum(hs * wsp);
    float t = ux / fmaxf(h0, MIN_NORM);

    // expmap([t,wsp], h)
    float md = wsum(wsp * wsp) - t * t;    // minkowski dot
    float normu = fminf(sqrtf(fmaxf(md, EPS)), MAX_NORM);
    float theta = fmaxf(normu, MIN_NORM);
    float ch = coshf(theta);
    float shot = sinhf(theta) / theta;
    float u_pt = (lane == 0) ? t : wsp;
    float res = ch * h + shot * u_pt;
    // proj
    float rsp = (lane == 0) ? 0.f : res;
    float rn2 = wsum(rsp * rsp);
    float rtime = sqrtf(fmaxf(1.f + rn2, EPS));
    res = (lane == 0) ? rtime : res;

    // xt = logmap0(res)
    buf[pt * 64 + lane] = logmap0_pt(res, lane);
}

__global__ void zero_kernel(int* __restrict__ p, int n) {
    int i = blockIdx.x * 256 + threadIdx.x;
    if (i < n) p[i] = 0;
}

__global__ void hist_kernel(const int* __restrict__ row, int* __restrict__ counts, int E) {
    int e = blockIdx.x * 256 + threadIdx.x;
    if (e < E) atomicAdd(&counts[row[e]], 1);
}

__global__ __launch_bounds__(1024) void scan_kernel(const int* __restrict__ counts,
                                                    int* __restrict__ starts, int n) {
    __shared__ int lds[1024];
    __shared__ int s_carry;
    int tid = threadIdx.x;
    if (tid == 0) s_carry = 0;
    __syncthreads();
    for (int base = 0; base < n; base += 1024) {
        int v = (base + tid < n) ? counts[base + tid] : 0;
        lds[tid] = v;
        __syncthreads();
        for (int off = 1; off < 1024; off <<= 1) {
            int t = 0;
            if (tid >= off) t = lds[tid - off];
            __syncthreads();
            lds[tid] += t;
            __syncthreads();
        }
        int incl = lds[tid];
        int c = s_carry;
        if (base + tid < n) starts[base + tid] = c + incl - v;  // exclusive
        __syncthreads();
        if (tid == 1023) s_carry = c + lds[1023];
        __syncthreads();
    }
    if (tid == 0) starts[n] = s_carry;
}

__global__ void scatter_kernel(const int* __restrict__ row, const int* __restrict__ starts,
                               int* __restrict__ cursor, int* __restrict__ edge_idx, int E) {
    int e = blockIdx.x * 256 + threadIdx.x;
    if (e < E) {
        int r = row[e];
        int p = atomicAdd(&cursor[r], 1);
        edge_idx[starts[r] + p] = e;
    }
}

// one block per row: support[r,:] = min( sum_e val[e]*xt[col[e],:], MAX_NORM )
__global__ __launch_bounds__(256) void spmm_kernel(const float* __restrict__ xt,
                                                   const float* __restrict__ val,
                                                   const int* __restrict__ col,
                                                   const int* __restrict__ starts,
                                                   const int* __restrict__ edge_idx,
                                                   float* __restrict__ out) {
    int r = blockIdx.x;
    int d = threadIdx.x;
    int s = starts[r], e = starts[r + 1];
    float acc = 0.f;
    for (int i = s; i < e; i++) {
        int eid = edge_idx[i];
        int c = col[eid];
        float v = val[eid];
        acc = fmaf(v, xt[(size_t)c * 256 + d], acc);
    }
    out[(size_t)r * 256 + d] = fminf(acc, MAX_NORM);
}

// support (clamped) -> out in place: expmap0+proj, logmap0, relu-clamp, expmap0+proj
__global__ __launch_bounds__(256) void final_kernel(float* __restrict__ buf) {
    int lane = threadIdx.x & 63;
    int w = threadIdx.x >> 6;
    long pt = (long)blockIdx.x * 4 + w;
    float s = buf[pt * 64 + lane];
    float h = expmap0_proj_pt(s, lane);
    float t = logmap0_pt(h, lane);
    t = fminf(fmaxf(t, 0.f), MAX_NORM);
    float o = expmap0_proj_pt(t, lane);
    buf[pt * 64 + lane] = o;
}

extern "C" void kernel_launch(void* const* d_in, const int* in_sizes, int n_in,
                              void* d_out, int out_size, void* d_ws, size_t ws_size,
                              hipStream_t stream) {
    const float* x       = (const float*)d_in[0];
    const float* adj_val = (const float*)d_in[1];
    const float* weight  = (const float*)d_in[2];
    const float* bias    = (const float*)d_in[3];
    const int*   adj_row = (const int*)d_in[4];
    const int*   adj_col = (const int*)d_in[5];
    float* out = (float*)d_out;

    const int N = NN, E = EE;

    // workspace layout
    float* B      = (float*)d_ws;            // N*256 floats (mu/xt)
    float* Wt     = B + (size_t)N * 256;     // 65536 floats
    int* counts   = (int*)(Wt + 65536);      // N
    int* cursor   = counts + N;              // N   (contiguous with counts for one zero pass)
    int* starts   = cursor + N;              // N+1
    int* edge_idx = starts + N + 1;          // E

    // 1) u = logmap0(x)  -> use d_out as scratch
    logmap0_kernel<<<N, 256, 0, stream>>>(x, out);
    // 2) Wt = W^T
    transpose_kernel<<<256, 256, 0, stream>>>(weight, Wt);
    // 3) mu = u @ W^T
    gemm_kernel<<<N / GEMM_R, 256, 0, stream>>>(out, Wt, B, N);
    // 4) mu -> xt (in place, fused hyperbolic middle section)
    hyp_mid_kernel<<<N, 256, 0, stream>>>(B, bias);
    // 5) CSR build
    zero_kernel<<<(2 * N + 255) / 256, 256, 0, stream>>>(counts, 2 * N);
    hist_kernel<<<(E + 255) / 256, 256, 0, stream>>>(adj_row, counts, E);
    scan_kernel<<<1, 1024, 0, stream>>>(counts, starts, N);
    scatter_kernel<<<(E + 255) / 256, 256, 0, stream>>>(adj_row, starts, cursor, edge_idx, E);
    // 6) support = segment_sum(val * xt[col]) with clamp -> d_out
    spmm_kernel<<<N, 256, 0, stream>>>(B, adj_val, adj_col, starts, edge_idx, out);
    // 7) final pointwise chain in place on d_out
    final_kernel<<<N, 256, 0, stream>>>(out);
}

// Round 2
// 336.418 us; speedup vs baseline: 1.5932x; 1.5932x over previous
//
#include <hip/hip_runtime.h>
#include <hip/hip_bf16.h>

#define MIN_NORM 1e-15f
#define EPS 1e-7f
#define MAX_NORM 1000.0f

#define NN 30000
#define PP 4
#define DD 64
#define EE 480000

__device__ inline float frcp(float x) { return __builtin_amdgcn_rcpf(x); }

// ---------- wave-wide helpers (wave = 64 lanes = one point of D=64) ----------
__device__ inline float wsum(float v) {
#pragma unroll
    for (int off = 32; off >= 1; off >>= 1) v += __shfl_xor(v, off, 64);
    return v;
}

// logmap0 (K=1): x point per-lane (lane0 = time). returns tangent per-lane (lane0=0).
__device__ inline float logmap0_pt(float x, int lane) {
    float sp = (lane == 0) ? 0.f : x;
    float n2 = wsum(sp * sp);
    float n = fmaxf(sqrtf(n2), MIN_NORM);
    float x0 = __shfl(x, 0, 64);
    float th = fmaxf(x0, 1.f + EPS);
    float ac = __logf(th + sqrtf(fmaxf(th * th - 1.f, MIN_NORM)));
    return (lane == 0) ? 0.f : (ac * sp * frcp(n));
}

// expmap0 (K=1) followed by proj: input tangent per-lane (lane0 ignored). returns point.
__device__ inline float expmap0_proj_pt(float v, int lane) {
    float sp = (lane == 0) ? 0.f : v;
    float n2 = wsum(sp * sp);
    float n = fmaxf(sqrtf(n2), MIN_NORM);
    float ep = __expf(n), em = frcp(ep);
    float s = 0.5f * (ep - em) * frcp(n);
    float time = sqrtf(fmaxf(1.f + s * s * n2, EPS));
    return (lane == 0) ? time : s * sp;
}

// ---------- 16-lane-group helpers (lane group = one point, 4 floats/lane) ----------
__device__ inline float gsum16(float v) {
#pragma unroll
    for (int off = 8; off >= 1; off >>= 1) v += __shfl_xor(v, off, 64);
    return v;
}

__device__ inline float4 expmap0_proj_g16(float4 v, int lane) {
    bool leader = ((lane & 15) == 0);
    float4 sp = v;
    if (leader) sp.x = 0.f;
    float n2 = gsum16(sp.x * sp.x + sp.y * sp.y + sp.z * sp.z + sp.w * sp.w);
    float n = fmaxf(sqrtf(n2), MIN_NORM);
    float ep = __expf(n), em = frcp(ep);
    float s = 0.5f * (ep - em) * frcp(n);
    float time = sqrtf(fmaxf(1.f + s * s * n2, EPS));
    float4 r;
    r.x = leader ? time : s * sp.x;
    r.y = s * sp.y;
    r.z = s * sp.z;
    r.w = s * sp.w;
    return r;
}

__device__ inline float4 logmap0_g16(float4 xp, int lane) {
    bool leader = ((lane & 15) == 0);
    float4 sp = xp;
    if (leader) sp.x = 0.f;
    float n2 = gsum16(sp.x * sp.x + sp.y * sp.y + sp.z * sp.z + sp.w * sp.w);
    float n = fmaxf(sqrtf(n2), MIN_NORM);
    float x0 = __shfl(xp.x, lane & 48, 64);  // group leader's time
    float th = fmaxf(x0, 1.f + EPS);
    float ac = __logf(th + sqrtf(fmaxf(th * th - 1.f, MIN_NORM)));
    float sc = ac * frcp(n);
    float4 r;
    r.x = sc * sp.x;  // leader: sp.x==0 -> 0
    r.y = sc * sp.y;
    r.z = sc * sp.z;
    r.w = sc * sp.w;
    return r;
}

// ---------- pack W for the fused GEMM: Wt2[(k>>2)*1024 + j*4 + (k&3)] = W[j][k] ----------
__global__ void transpose_kernel(const float* __restrict__ w, float* __restrict__ wt2) {
    int j = blockIdx.x;
    int k = threadIdx.x;
    wt2[(k >> 2) * 1024 + j * 4 + (k & 3)] = w[j * 256 + k];
}

// ---------- fused: logmap0(x) -> GEMM(@W^T) -> expmap0/mobius_add(bias)/logmap0 -> xt ----------
#define GR 16
__global__ __launch_bounds__(256) void fused_front_kernel(const float* __restrict__ x,
                                                          const float* __restrict__ wt2,
                                                          const float* __restrict__ bias,
                                                          float* __restrict__ xt) {
    __shared__ float4 ulds4[GR][64];
    float* ulds = (float*)ulds4;  // [GR][256]
    int tid = threadIdx.x;
    int lane = tid & 63;
    int row0 = blockIdx.x * GR;

    // prologue: u = logmap0(x) into LDS (wave p reduces point p of each row)
#pragma unroll
    for (int i = 0; i < GR; i++) {
        float xv = x[(size_t)(row0 + i) * 256 + tid];
        ulds[i * 256 + tid] = logmap0_pt(xv, lane);
    }
    __syncthreads();

    // GEMM: acc[i] = sum_k u[i][k] * W[tid][k]
    float acc[GR];
#pragma unroll
    for (int i = 0; i < GR; i++) acc[i] = 0.f;
    const float4* wt4 = (const float4*)wt2;
    for (int kc = 0; kc < 64; kc++) {
        float4 wv = wt4[kc * 256 + tid];
#pragma unroll
        for (int i = 0; i < GR; i++) {
            float4 uv = ulds4[i][kc];
            acc[i] = fmaf(uv.x, wv.x, acc[i]);
            acc[i] = fmaf(uv.y, wv.y, acc[i]);
            acc[i] = fmaf(uv.z, wv.z, acc[i]);
            acc[i] = fmaf(uv.w, wv.w, acc[i]);
        }
    }

    // hoisted per-point bias terms (wave p == point p)
    int p = tid >> 6;
    float b = bias[p * 64 + lane];
    float y = expmap0_proj_pt(b, lane);
    float usp = logmap0_pt(y, lane);  // lane0 = 0

    // epilogue: hyp_mid on each row's point p
#pragma unroll
    for (int i = 0; i < GR; i++) {
        float mu = acc[i];
        float h = expmap0_proj_pt(mu, lane);
        float h0 = __shfl(h, 0, 64);
        float hs = (lane == 0) ? 0.f : h;

        float yn = fmaxf(sqrtf(wsum(hs * hs)), MIN_NORM);
        float yu = hs * frcp(yn);
        float alpha = wsum((lane == 0) ? 0.f : (yu * usp));
        float wsp = (lane == 0) ? 0.f : (usp - alpha * (1.f - h0) * yu);

        float ux = wsum(hs * wsp);
        float t = ux * frcp(fmaxf(h0, MIN_NORM));

        float md = wsum(wsp * wsp) - t * t;
        float normu = fminf(sqrtf(fmaxf(md, EPS)), MAX_NORM);
        float theta = fmaxf(normu, MIN_NORM);
        float ep = __expf(theta), em = frcp(ep);
        float ch = 0.5f * (ep + em);
        float shot = 0.5f * (ep - em) * frcp(theta);
        float u_pt = (lane == 0) ? t : wsp;
        float res = ch * h + shot * u_pt;

        float rsp = (lane == 0) ? 0.f : res;
        float rn2 = wsum(rsp * rsp);
        res = (lane == 0) ? sqrtf(fmaxf(1.f + rn2, EPS)) : res;

        xt[(size_t)(row0 + i) * 256 + tid] = logmap0_pt(res, lane);
    }
}

// ---------- CSR build ----------
__global__ void zero_kernel(int* __restrict__ p, int n) {
    int i = blockIdx.x * 256 + threadIdx.x;
    if (i < n) p[i] = 0;
}

__global__ void hist_kernel(const int* __restrict__ row, int* __restrict__ counts, int E) {
    int e = blockIdx.x * 256 + threadIdx.x;
    if (e < E) atomicAdd(&counts[row[e]], 1);
}

__global__ __launch_bounds__(1024) void scan_kernel(const int* __restrict__ counts,
                                                    int* __restrict__ starts, int n) {
    __shared__ int lds[1024];
    __shared__ int s_carry;
    int tid = threadIdx.x;
    if (tid == 0) s_carry = 0;
    __syncthreads();
    for (int base = 0; base < n; base += 1024) {
        int v = (base + tid < n) ? counts[base + tid] : 0;
        lds[tid] = v;
        __syncthreads();
        for (int off = 1; off < 1024; off <<= 1) {
            int t = 0;
            if (tid >= off) t = lds[tid - off];
            __syncthreads();
            lds[tid] += t;
            __syncthreads();
        }
        int incl = lds[tid];
        int c = s_carry;
        if (base + tid < n) starts[base + tid] = c + incl - v;  // exclusive
        __syncthreads();
        if (tid == 1023) s_carry = c + lds[1023];
        __syncthreads();
    }
    if (tid == 0) starts[n] = s_carry;
}

__global__ void scatter_kernel(const int* __restrict__ row, const int* __restrict__ starts,
                               int* __restrict__ cursor, int* __restrict__ edge_idx, int E) {
    int e = blockIdx.x * 256 + threadIdx.x;
    if (e < E) {
        int r = row[e];
        int p = atomicAdd(&cursor[r], 1);
        edge_idx[starts[r] + p] = e;
    }
}

// ---------- SpMM (wave per row, float4 lanes, unroll-4) + fused final chain ----------
__global__ __launch_bounds__(256) void spmm_final_kernel(const float4* __restrict__ xt4,
                                                         const float* __restrict__ val,
                                                         const int* __restrict__ col,
                                                         const int* __restrict__ starts,
                                                         const int* __restrict__ eidx,
                                                         float4* __restrict__ out4) {
    int w = threadIdx.x >> 6;
    int lane = threadIdx.x & 63;
    int r = blockIdx.x * 4 + w;
    int s = starts[r], e = starts[r + 1];

    float4 acc = {0.f, 0.f, 0.f, 0.f};
    int i = s;
    for (; i + 4 <= e; i += 4) {
        int e0 = eidx[i], e1 = eidx[i + 1], e2 = eidx[i + 2], e3 = eidx[i + 3];
        int c0 = col[e0], c1 = col[e1], c2 = col[e2], c3 = col[e3];
        float v0 = val[e0], v1 = val[e1], v2 = val[e2], v3 = val[e3];
        float4 x0 = xt4[(size_t)c0 * 64 + lane];
        float4 x1 = xt4[(size_t)c1 * 64 + lane];
        float4 x2 = xt4[(size_t)c2 * 64 + lane];
        float4 x3 = xt4[(size_t)c3 * 64 + lane];
        acc.x = fmaf(v0, x0.x, acc.x); acc.y = fmaf(v0, x0.y, acc.y);
        acc.z = fmaf(v0, x0.z, acc.z); acc.w = fmaf(v0, x0.w, acc.w);
        acc.x = fmaf(v1, x1.x, acc.x); acc.y = fmaf(v1, x1.y, acc.y);
        acc.z = fmaf(v1, x1.z, acc.z); acc.w = fmaf(v1, x1.w, acc.w);
        acc.x = fmaf(v2, x2.x, acc.x); acc.y = fmaf(v2, x2.y, acc.y);
        acc.z = fmaf(v2, x2.z, acc.z); acc.w = fmaf(v2, x2.w, acc.w);
        acc.x = fmaf(v3, x3.x, acc.x); acc.y = fmaf(v3, x3.y, acc.y);
        acc.z = fmaf(v3, x3.z, acc.z); acc.w = fmaf(v3, x3.w, acc.w);
    }
    for (; i < e; i++) {
        int e0 = eidx[i];
        int c0 = col[e0];
        float v0 = val[e0];
        float4 x0 = xt4[(size_t)c0 * 64 + lane];
        acc.x = fmaf(v0, x0.x, acc.x); acc.y = fmaf(v0, x0.y, acc.y);
        acc.z = fmaf(v0, x0.z, acc.z); acc.w = fmaf(v0, x0.w, acc.w);
    }

    // support clamp
    acc.x = fminf(acc.x, MAX_NORM); acc.y = fminf(acc.y, MAX_NORM);
    acc.z = fminf(acc.z, MAX_NORM); acc.w = fminf(acc.w, MAX_NORM);

    // fused final: expmap0+proj -> logmap0 -> relu/clamp -> expmap0+proj
    float4 h = expmap0_proj_g16(acc, lane);
    float4 t = logmap0_g16(h, lane);
    t.x = fminf(fmaxf(t.x, 0.f), MAX_NORM);
    t.y = fminf(fmaxf(t.y, 0.f), MAX_NORM);
    t.z = fminf(fmaxf(t.z, 0.f), MAX_NORM);
    t.w = fminf(fmaxf(t.w, 0.f), MAX_NORM);
    float4 o = expmap0_proj_g16(t, lane);

    out4[(size_t)r * 64 + lane] = o;
}

extern "C" void kernel_launch(void* const* d_in, const int* in_sizes, int n_in,
                              void* d_out, int out_size, void* d_ws, size_t ws_size,
                              hipStream_t stream) {
    const float* x       = (const float*)d_in[0];
    const float* adj_val = (const float*)d_in[1];
    const float* weight  = (const float*)d_in[2];
    const float* bias    = (const float*)d_in[3];
    const int*   adj_row = (const int*)d_in[4];
    const int*   adj_col = (const int*)d_in[5];
    float* out = (float*)d_out;

    const int N = NN, E = EE;

    // workspace layout (identical footprint to round 1 — proven to fit)
    float* B      = (float*)d_ws;            // N*256 floats (xt)
    float* Wt2    = B + (size_t)N * 256;     // 65536 floats
    int* counts   = (int*)(Wt2 + 65536);     // N
    int* cursor   = counts + N;              // N
    int* starts   = cursor + N;              // N+1
    int* edge_idx = starts + N + 1;          // E

    transpose_kernel<<<256, 256, 0, stream>>>(weight, Wt2);
    fused_front_kernel<<<N / GR, 256, 0, stream>>>(x, Wt2, bias, B);

    zero_kernel<<<(2 * N + 255) / 256, 256, 0, stream>>>(counts, 2 * N);
    hist_kernel<<<(E + 255) / 256, 256, 0, stream>>>(adj_row, counts, E);
    scan_kernel<<<1, 1024, 0, stream>>>(counts, starts, N);
    scatter_kernel<<<(E + 255) / 256, 256, 0, stream>>>(adj_row, starts, cursor, edge_idx, E);

    spmm_final_kernel<<<N / 4, 256, 0, stream>>>((const float4*)B, adj_val, adj_col,
                                                 starts, edge_idx, (float4*)out);
}